// Round 11
// baseline (28.713 us; speedup 1.0000x reference)
//
#include <hip/hip_runtime.h>
#include <math.h>

#define N_PTS 16384
#define WAVE_P 128                 // p-cols per wave (4 B-frags x 32)
#define BLK_P  512                 // p per block (4 waves)
#define NPB    (N_PTS / BLK_P)     // 32
#define CHUNK_G 512                // g per chunk
#define NCH    (N_PTS / CHUNK_G)   // 32
#define NGROUP (CHUNK_G / 32)      // 16 A-groups per chunk
#define ROWS   24                  // shorts per padded LDS A-row (48 B, 16B-aligned)
#define NFBLK  64                  // fin blocks (256 points each)

typedef __attribute__((ext_vector_type(8)))  short short8_t;
typedef __attribute__((ext_vector_type(16))) float f32x16;

// --- bf16 helpers (round-to-nearest-even) ---
__device__ __forceinline__ unsigned short bf_rn(float x) {
    unsigned u = __float_as_uint(x);
    unsigned r = (u + 0x7fffu + ((u >> 16) & 1u)) >> 16;
    return (unsigned short)r;
}
__device__ __forceinline__ float bf_up(unsigned short s) {
    return __uint_as_float(((unsigned)s) << 16);
}
__device__ __forceinline__ unsigned enc_f32(float f) {
    unsigned b = __float_as_uint(f);
    return (b & 0x80000000u) ? ~b : (b | 0x80000000u);
}
__device__ __forceinline__ float dec_f32(unsigned k) {
    unsigned b = (k & 0x80000000u) ? (k & 0x7fffffffu) : ~k;
    return __uint_as_float(b);
}
__device__ __forceinline__ float min3f(float a, float b, float c) {
    return fminf(fminf(a, b), c);      // -> v_min3_f32
}
__device__ __forceinline__ short8_t pack8(unsigned short a0, unsigned short a1,
        unsigned short a2, unsigned short a3, unsigned short a4,
        unsigned short a5, unsigned short a6, unsigned short a7) {
    union { unsigned short u[8]; short8_t v; } x;
    x.u[0]=a0; x.u[1]=a1; x.u[2]=a2; x.u[3]=a3;
    x.u[4]=a4; x.u[5]=a5; x.u[6]=a6; x.u[7]=a7;
    return x.v;
}

// 16-value + carry min via v_min3 chains: 9 ops.
__device__ __forceinline__ float tree16c(f32x16 d, float carry) {
    float m0 = min3f(d[0],  d[1],  d[2]);
    float m1 = min3f(d[3],  d[4],  d[5]);
    float m2 = min3f(d[6],  d[7],  d[8]);
    float m3 = min3f(d[9],  d[10], d[11]);
    float m4 = min3f(d[12], d[13], d[14]);
    float m5 = min3f(m4, d[15], carry);
    return min3f(m0, m1, min3f(m2, m3, m5));
}

// Fused transform + MFMA NN. Grid (NPB, NCH).
// A rows (g side) staged in LDS by the block (48B-padded); B frags (p side)
// computed per-lane in registers. Hot loop = r7/r10 anchor.
// Epilogue: ATOMIC ? atomicMin(keys) : plain partial-row stores (no init needed).
template<bool ATOMIC>
__global__ __launch_bounds__(256) void k_nn_fused(
        const float* __restrict__ R, const float* __restrict__ t,
        const float* __restrict__ m, const float* __restrict__ g,
        float* __restrict__ partial /* or unsigned* keys when ATOMIC */) {
    __shared__ unsigned short sgA[CHUNK_G * ROWS];   // 24 KB
    const int tid = threadIdx.x;
    const int wid = tid >> 6, l = tid & 63;
    const int lc = l & 31, lh = l >> 5;
    const int pbase = blockIdx.x * BLK_P + wid * WAVE_P;
    const int gch = blockIdx.y * CHUNK_G;

    // uniform rotation/translation (scalar loads)
    const float r0=R[0], r1=R[1], r2=R[2], r3=R[3], r4=R[4],
                r5=R[5], r6=R[6], r7=R[7], r8=R[8];
    const float t0=t[0], t1=t[1], t2=t[2];

    // ---- stage A rows: 2 g-points per thread ----
    #pragma unroll
    for (int k = 0; k < 2; ++k) {
        int r = k * 256 + tid;             // row within chunk
        int n = gch + r;
        float gx = g[3*n+0], gy = g[3*n+1], gz = g[3*n+2];
        float gg = fmaf(gx,gx,fmaf(gy,gy,gz*gz));
        unsigned short ghx = bf_rn(gx), ghy = bf_rn(gy), ghz = bf_rn(gz);
        unsigned short glx = bf_rn(gx - bf_up(ghx)),
                       gly = bf_rn(gy - bf_up(ghy)),
                       glz = bf_rn(gz - bf_up(ghz));
        unsigned short ggh = bf_rn(gg), ggl = bf_rn(gg - bf_up(ggh));
        short8_t h0 = pack8(ghx, ghy, ghz, ghx, ghy, ghz, ggh, ggl);
        short8_t h1 = pack8(glx, gly, glz, 0, 0, 0, 0, 0);
        *(short8_t*)(sgA + (size_t)r * ROWS)     = h0;
        *(short8_t*)(sgA + (size_t)r * ROWS + 8) = h1;
    }

    // ---- B frags per-lane (4 p-points; lane builds exactly its 8 shorts) ----
    short8_t Bf[4];
    #pragma unroll
    for (int f = 0; f < 4; ++f) {
        int n = pbase + f * 32 + lc;
        float mx = m[3*n+0], my = m[3*n+1], mz = m[3*n+2];
        float px = fmaf(r0,mx,fmaf(r1,my,r2*mz)) + t0;
        float py = fmaf(r3,mx,fmaf(r4,my,r5*mz)) + t1;
        float pz = fmaf(r6,mx,fmaf(r7,my,r8*mz)) + t2;
        float Px = -2.f*px, Py = -2.f*py, Pz = -2.f*pz;
        unsigned short phx = bf_rn(Px), phy = bf_rn(Py), phz = bf_rn(Pz);
        if (lh == 0) {
            unsigned short plx = bf_rn(Px - bf_up(phx)),
                           ply = bf_rn(Py - bf_up(phy)),
                           plz = bf_rn(Pz - bf_up(phz));
            Bf[f] = pack8(phx, phy, phz, plx, ply, plz, 0x3F80, 0x3F80);
        } else {
            Bf[f] = pack8(phx, phy, phz, 0, 0, 0, 0, 0);
        }
    }
    __syncthreads();

    // ---- hot loop (anchor): 16 groups x (4 MFMA + min3 trees) ----
    const f32x16 zc = {};
    float rm0 = 3.4e38f, rm1 = 3.4e38f, rm2 = 3.4e38f, rm3 = 3.4e38f;

    const unsigned short* abase = sgA + (size_t)lc * ROWS + lh * 8;
    short8_t a = *(const short8_t*)abase;
    #pragma unroll 2
    for (int gi = 0; gi < NGROUP; ++gi) {
        short8_t an = (gi + 1 < NGROUP)
                      ? *(const short8_t*)(abase + (size_t)(gi + 1) * 32 * ROWS) : a;
        {   // pair 0/1 — only 2 D tiles live at once
            f32x16 d0 = __builtin_amdgcn_mfma_f32_32x32x16_bf16(a, Bf[0], zc, 0, 0, 0);
            f32x16 d1 = __builtin_amdgcn_mfma_f32_32x32x16_bf16(a, Bf[1], zc, 0, 0, 0);
            rm0 = tree16c(d0, rm0);
            rm1 = tree16c(d1, rm1);
        }
        {   // pair 2/3
            f32x16 d2 = __builtin_amdgcn_mfma_f32_32x32x16_bf16(a, Bf[2], zc, 0, 0, 0);
            f32x16 d3 = __builtin_amdgcn_mfma_f32_32x32x16_bf16(a, Bf[3], zc, 0, 0, 0);
            rm2 = tree16c(d2, rm2);
            rm3 = tree16c(d3, rm3);
        }
        a = an;
    }

    // merge row-halves (lanes l and l^32: same column, disjoint g-rows)
    rm0 = fminf(rm0, __shfl_xor(rm0, 32, 64));
    rm1 = fminf(rm1, __shfl_xor(rm1, 32, 64));
    rm2 = fminf(rm2, __shfl_xor(rm2, 32, 64));
    rm3 = fminf(rm3, __shfl_xor(rm3, 32, 64));

    if (lh == 0) {
        if (ATOMIC) {
            unsigned* keys = (unsigned*)partial;
            atomicMin(&keys[pbase + lc],      enc_f32(rm0));
            atomicMin(&keys[pbase + 32 + lc], enc_f32(rm1));
            atomicMin(&keys[pbase + 64 + lc], enc_f32(rm2));
            atomicMin(&keys[pbase + 96 + lc], enc_f32(rm3));
        } else {
            float* row = partial + (size_t)blockIdx.y * N_PTS + pbase + lc;
            row[0]  = rm0;
            row[32] = rm1;
            row[64] = rm2;
            row[96] = rm3;
        }
    }
}

// Fin: pp computed inline; min over 32 partial rows (or key decode);
// dis = sqrt(max(pp + smin, 0)); block-reduce -> psum. No atomics/fences.
template<bool ATOMIC>
__global__ __launch_bounds__(256) void k_fin(
        const float* __restrict__ R, const float* __restrict__ t,
        const float* __restrict__ m, const float* __restrict__ g,
        const float* __restrict__ partial, const int* __restrict__ midx,
        float* __restrict__ psum) {
    const int tid = threadIdx.x;
    const int n = blockIdx.x * 256 + tid;
    const bool sym = (midx[0] == 0);

    float mx = m[3*n+0], my = m[3*n+1], mz = m[3*n+2];
    float px = fmaf(R[0],mx,fmaf(R[1],my,R[2]*mz)) + t[0];
    float py = fmaf(R[3],mx,fmaf(R[4],my,R[5]*mz)) + t[1];
    float pz = fmaf(R[6],mx,fmaf(R[7],my,R[8]*mz)) + t[2];

    float dis;
    if (sym) {
        float smin;
        if (ATOMIC) {
            smin = dec_f32(((const unsigned*)partial)[n]);
        } else {
            smin = 3.4e38f;
            #pragma unroll 8
            for (int c = 0; c < NCH; ++c)
                smin = fminf(smin, partial[(size_t)c * N_PTS + n]);
        }
        float pp = fmaf(px,px,fmaf(py,py,pz*pz));
        dis = sqrtf(fmaxf(pp + smin, 0.f));
    } else {
        float dx = px - g[3*n+0], dy = py - g[3*n+1], dz = pz - g[3*n+2];
        dis = sqrtf(fmaf(dx,dx,fmaf(dy,dy,dz*dz)));
    }
    #pragma unroll
    for (int off = 32; off > 0; off >>= 1) dis += __shfl_down(dis, off, 64);
    __shared__ float sred[4];
    if ((tid & 63) == 0) sred[tid >> 6] = dis;
    __syncthreads();
    if (tid == 0) psum[blockIdx.x] = (sred[0] + sred[1]) + (sred[2] + sred[3]);
}

// Final: sum psum[NFBLK] -> mean.
__global__ void k_final(const float* __restrict__ psum, float* __restrict__ out) {
    float v = psum[threadIdx.x];
    #pragma unroll
    for (int off = 32; off > 0; off >>= 1) v += __shfl_down(v, off, 64);
    if (threadIdx.x == 0) out[0] = v / (float)N_PTS;
}

extern "C" void kernel_launch(void* const* d_in, const int* in_sizes, int n_in,
                              void* d_out, int out_size, void* d_ws, size_t ws_size,
                              hipStream_t stream) {
    const float* R   = (const float*)d_in[0];
    const float* t   = (const float*)d_in[1];
    const float* m   = (const float*)d_in[2];
    const float* g   = (const float*)d_in[3];
    const int* midx  = (const int*)d_in[4];

    char* ws = (char*)d_ws;
    float* out = (float*)d_out;

    const size_t partial_bytes = (size_t)NCH * N_PTS * 4;   // 2 MB
    if (ws_size >= partial_bytes + 1024) {
        // main path: plain partial-row stores, no init needed anywhere
        float* partial = (float*)ws;
        float* psum    = (float*)(ws + partial_bytes);
        k_nn_fused<false><<<dim3(NPB, NCH), dim3(256), 0, stream>>>(
            R, t, m, g, partial);
        k_fin<false><<<dim3(NFBLK), dim3(256), 0, stream>>>(
            R, t, m, g, partial, midx, psum);
        k_final<<<dim3(1), dim3(64), 0, stream>>>(psum, out);
    } else {
        // small-ws fallback: atomicMin keys (64 KB) + memset init
        unsigned* keys = (unsigned*)ws;
        float*    psum = (float*)(ws + (size_t)N_PTS * 4);
        hipMemsetAsync(keys, 0xFF, (size_t)N_PTS * 4, stream);
        k_nn_fused<true><<<dim3(NPB, NCH), dim3(256), 0, stream>>>(
            R, t, m, g, (float*)keys);
        k_fin<true><<<dim3(NFBLK), dim3(256), 0, stream>>>(
            R, t, m, g, (const float*)keys, midx, psum);
        k_final<<<dim3(1), dim3(64), 0, stream>>>(psum, out);
    }
}